// Round 9
// baseline (131.690 us; speedup 1.0000x reference)
//
#include <hip/hip_runtime.h>
#include <stdint.h>

#define HH 224
#define WW 224
#define BB 4
#define PP 7          // seams per direction
#define SEG 28
#define BW 5
#define MM 11         // 2*BW+1

#define POS_INF_I 0x7F800000

typedef const __attribute__((address_space(1))) unsigned int* gas_ptr;
typedef __attribute__((address_space(3))) unsigned int* las_ptr;

// map-compose for 11-entry 4-bit-nibble maps packed in u64:  H[i] = F[G[i]]
__device__ inline unsigned long long mcompose(unsigned long long F, unsigned long long G) {
    unsigned long long H = 0ull;
#pragma unroll
    for (int i = 0; i < 11; ++i) {
        unsigned g = (unsigned)(G >> (4 * i)) & 15u;
        H |= ((F >> (4 * g)) & 15ull) << (4 * i);
    }
    return H;
}

// ---------------------------------------------------------------------------
// DP kernel (unchanged from R4 — verified absmax 0)
// ---------------------------------------------------------------------------
__global__ __launch_bounds__(64) void dp_kernel(const float* __restrict__ grad,
                                                int* __restrict__ coords_v,
                                                int* __restrict__ coords_h) {
    __shared__ __align__(16) float gseg[225 * 16];

    const int tid = threadIdx.x;
    const int l   = tid & 15;
    const int sid = blockIdx.x;
    const int p   = sid % PP;
    const int dir = (sid / PP) & 1;
    const int b   = sid / (2 * PP);
    const int base = SEG * (p + 1);
    const float* gb = grad + b * (HH * WW);

    {
        const int r  = tid >> 4;
        const int m  = tid & 15;
        const int sS = (dir == 0) ? WW : 1;
        const int sM = (dir == 0) ? 1  : WW;
        const float* src = gb + r * sS + (base - BW + m) * sM;
        const long stepBytes = (long)(4 * sS) * 4;
#pragma unroll 8
        for (int c = 0; c < 56; ++c) {
            __builtin_amdgcn_global_load_lds((gas_ptr)(const void*)src,
                                             (las_ptr)(void*)(&gseg[c * 64]), 4, 0, 0);
            src = (const float*)((const char*)src + stepBytes);
        }
    }
    __syncthreads();

    const float lane_add = (l < MM) ? 0.0f : __int_as_float(POS_INF_I);
    const float* gp = &gseg[l];

    unsigned wreg[16] = {};

#define DP_STEP(gval, ownb, jj_c)                                                       \
    {                                                                                   \
        float v1 = cost;                                                                \
        float v0 = __int_as_float(__builtin_amdgcn_update_dpp(                          \
            POS_INF_I, __float_as_int(cost), 0x111, 0xf, 0xf, false));                  \
        float v2 = __int_as_float(__builtin_amdgcn_update_dpp(                          \
            POS_INF_I, __float_as_int(cost), 0x101, 0xf, 0xf, false));                  \
        bool a01 = (v0 <= v1), a02 = (v0 <= v2), a12 = (v1 <= v2);                      \
        bool aa  = a01 && a02;                                                          \
        unsigned long long A   = __ballot(aa);                                          \
        unsigned long long C12 = __ballot(a12);                                         \
        unsigned long long B0 = ~A & C12;                                               \
        unsigned long long B1 = ~A & ~C12;                                              \
        float mv = aa ? v0 : (a12 ? v1 : v2);                                           \
        cost = mv - (gval) + lane_add;                                                  \
        unsigned wv = (unsigned)(B0 & 0x7FFull) | ((unsigned)(B1 & 0x7FFull) << 11);    \
        wreg[(jj_c)] = (ownb) ? wv : wreg[(jj_c)];                                      \
    }

    float cost = -gp[0] + lane_add;
    float buf[16], c0[16];
#pragma unroll
    for (int k = 0; k < 16; ++k) buf[k] = gp[(1 + k) * 16];
    for (int t = 0; t < 13; ++t) {
        const bool own = (tid == t);
#pragma unroll
        for (int k = 0; k < 16; ++k) c0[k] = buf[k];
#pragma unroll
        for (int k = 0; k < 16; ++k) buf[k] = gp[(16 * (t + 1) + 1 + k) * 16];
#pragma unroll
        for (int k = 0; k < 16; ++k) DP_STEP(c0[k], own, k)
    }
    {
        const bool own = (tid == 13);
#pragma unroll
        for (int k = 0; k < 15; ++k) DP_STEP(buf[k], own, k)
    }
#undef DP_STEP

    float bc = cost;
    int   bi = l;
#pragma unroll
    for (int mask = 1; mask < 16; mask <<= 1) {
        float oc = __shfl_xor(bc, mask, 16);
        int   oi = __shfl_xor(bi, mask, 16);
        if (oc < bc || (oc == bc && oi < bi)) { bc = oc; bi = oi; }
    }
    const int idx_last = bi;

    const int mcnt = (l < 13) ? 16 : ((l == 13) ? 15 : 0);
    const unsigned long long IDMAP = 0xA9876543210ull;
    unsigned long long L = IDMAP;
#pragma unroll
    for (int jj = 15; jj >= 0; --jj) {
        if (jj < mcnt) {
            unsigned ww = wreg[jj];
            unsigned long long M = 0ull;
#pragma unroll
            for (int i = 0; i < MM; ++i) {
                unsigned sel = ((ww >> i) & 1u) + 2u * ((ww >> (11 + i)) & 1u);
                M |= ((unsigned long long)(i + (int)sel - 1)) << (4 * i);
            }
            L = mcompose(M, L);
        }
    }
    unsigned long long I = L;
#pragma unroll
    for (int d = 1; d < 16; d <<= 1) {
        unsigned long long O = __shfl_down(I, d, 16);
        if (l + d < 16) I = mcompose(I, O);
    }
    unsigned long long R = __shfl_down(I, 1, 16);
    if (l == 15) R = IDMAP;

    int* cout = (dir == 0) ? coords_v : coords_h;
    if (tid == 15) cout[(b * HH + 223) * PP + p] = base + idx_last - BW;
    if (tid < 16) {
        unsigned v = (unsigned)(R >> (4 * idx_last)) & 15u;
#pragma unroll
        for (int jj = 15; jj >= 0; --jj) {
            if (jj < mcnt) {
                unsigned ww = wreg[jj];
                unsigned sel = ((ww >> v) & 1u) + 2u * ((ww >> (11 + v)) & 1u);
                v = v + sel - 1u;
                cout[(b * HH + (16 * l + jj)) * PP + p] = base + (int)v - BW;
            }
        }
    }
}

// ---------------------------------------------------------------------------
// labvote: initial labels (analytic, 38x14 LDS region) + vote iteration 1.
// Unchanged from R8 (proven). Grid (7,28,4) x (32,8).
// ---------------------------------------------------------------------------
#define RW 38
#define RH 14
#define RSTR 40

__global__ __launch_bounds__(256) void labvote_kernel(const int* __restrict__ cv,
                                                      const int* __restrict__ ch,
                                                      unsigned char* __restrict__ out8) {
    __shared__ unsigned char lab[RH * RSTR];
    __shared__ unsigned bins[16 * 256];
    const int tx = threadIdx.x, ty = threadIdx.y;
    const int t  = ty * 32 + tx;
    const int b  = blockIdx.z;
    const int GX0 = blockIdx.x * 32, GY0 = blockIdx.y * 8;

    for (int idx = t; idx < RW * RH; idx += 256) {
        int j = idx / RW, i = idx - j * RW;
        int gx = GX0 - 3 + i, gy = GY0 - 3 + j;
        if ((unsigned)gx < WW && (unsigned)gy < HH) {
            const int* cvp = cv + (b * HH + gy) * PP;
            const int* chp = ch + (b * WW + gx) * PP;
            int v = 0, h = 0;
#pragma unroll
            for (int q = 0; q < PP; ++q) { v += (cvp[q] <= gx); h += (chp[q] <= gy); }
            lab[j * RSTR + i] = (unsigned char)(v + 8 * h);
        }
    }
    __syncthreads();

    const int gx = GX0 + tx, gy = GY0 + ty;
#pragma unroll
    for (int c = 0; c < 16; ++c) bins[c * 256 + t] = 0u;
#pragma unroll
    for (int dy = -3; dy <= 3; ++dy) {
        if ((unsigned)(gy + dy) >= HH) continue;
#pragma unroll
        for (int dx = -3; dx <= 3; ++dx) {
            if ((unsigned)(gx + dx) >= WW) continue;
            int lb = lab[(ty + 3 + dy) * RSTR + (tx + 3 + dx)];
            int ay = dy < 0 ? -dy : dy, ax = dx < 0 ? -dx : dx;
            int d = ay > ax ? ay : ax;
            unsigned wgt = (d <= 1) ? 3u : (unsigned)(4 - d);
            atomicAdd(&bins[(lb >> 2) * 256 + t], wgt << ((lb & 3) * 8));
        }
    }
    int best_s = 0, best_k = 0;
#pragma unroll
    for (int c = 0; c < 16; ++c) {
        unsigned wd = bins[c * 256 + t];
        if (wd) {
#pragma unroll
            for (int q = 0; q < 4; ++q) {
                int s = (int)((wd >> (q * 8)) & 255u);
                if (s > best_s) { best_s = s; best_k = c * 4 + q; }
            }
        }
    }
    out8[(b * HH + gy) * WW + gx] = (unsigned char)best_k;
}

// ---------------------------------------------------------------------------
// votepair v2: 512 threads, 32x16 tile. Stage A: 38x22 intermediate region
// (1.63 px/thread) from global; stage B: own pixel from LDS. Grid (7,14,4).
// ---------------------------------------------------------------------------
#define RW2 38
#define RH2 22
#define RS2 40

__global__ __launch_bounds__(512) void votepair_kernel(const unsigned char* __restrict__ in,
                                                       unsigned char* __restrict__ out8,
                                                       int* __restrict__ out32) {
    __shared__ unsigned char mid[RH2 * RS2];
    __shared__ unsigned bins[16 * 512];
    const int tx = threadIdx.x, ty = threadIdx.y;
    const int t  = ty * 32 + tx;
    const int b  = blockIdx.z;
    const int GX0 = blockIdx.x * 32, GY0 = blockIdx.y * 16;
    const unsigned char* img = in + b * (HH * WW);

    // stage A: intermediate labels for the halo region (global-input histogram)
    for (int idx = t; idx < RW2 * RH2; idx += 512) {
        int j = idx / RW2, i = idx - j * RW2;
        int gx = GX0 - 3 + i, gy = GY0 - 3 + j;
        if ((unsigned)gx < WW && (unsigned)gy < HH) {
#pragma unroll
            for (int c = 0; c < 16; ++c) bins[c * 512 + t] = 0u;
#pragma unroll
            for (int dy = -3; dy <= 3; ++dy) {
                if ((unsigned)(gy + dy) >= HH) continue;
#pragma unroll
                for (int dx = -3; dx <= 3; ++dx) {
                    if ((unsigned)(gx + dx) >= WW) continue;
                    int lb = img[(gy + dy) * WW + (gx + dx)];
                    int ay = dy < 0 ? -dy : dy, ax = dx < 0 ? -dx : dx;
                    int d = ay > ax ? ay : ax;
                    unsigned wgt = (d <= 1) ? 3u : (unsigned)(4 - d);
                    atomicAdd(&bins[(lb >> 2) * 512 + t], wgt << ((lb & 3) * 8));
                }
            }
            int best_s = 0, best_k = 0;
#pragma unroll
            for (int c = 0; c < 16; ++c) {
                unsigned wd = bins[c * 512 + t];
                if (wd) {
#pragma unroll
                    for (int q = 0; q < 4; ++q) {
                        int s = (int)((wd >> (q * 8)) & 255u);
                        if (s > best_s) { best_s = s; best_k = c * 4 + q; }
                    }
                }
            }
            mid[j * RS2 + i] = (unsigned char)best_k;
        }
    }
    __syncthreads();

    // stage B: own pixel from LDS intermediates
    const int gx = GX0 + tx, gy = GY0 + ty;
#pragma unroll
    for (int c = 0; c < 16; ++c) bins[c * 512 + t] = 0u;
#pragma unroll
    for (int dy = -3; dy <= 3; ++dy) {
        if ((unsigned)(gy + dy) >= HH) continue;
#pragma unroll
        for (int dx = -3; dx <= 3; ++dx) {
            if ((unsigned)(gx + dx) >= WW) continue;
            int lb = mid[(ty + 3 + dy) * RS2 + (tx + 3 + dx)];
            int ay = dy < 0 ? -dy : dy, ax = dx < 0 ? -dx : dx;
            int d = ay > ax ? ay : ax;
            unsigned wgt = (d <= 1) ? 3u : (unsigned)(4 - d);
            atomicAdd(&bins[(lb >> 2) * 512 + t], wgt << ((lb & 3) * 8));
        }
    }
    int best_s = 0, best_k = 0;
#pragma unroll
    for (int c = 0; c < 16; ++c) {
        unsigned wd = bins[c * 512 + t];
        if (wd) {
#pragma unroll
            for (int q = 0; q < 4; ++q) {
                int s = (int)((wd >> (q * 8)) & 255u);
                if (s > best_s) { best_s = s; best_k = c * 4 + q; }
            }
        }
    }
    int o = (b * HH + gy) * WW + gx;
    if (out8)  out8[o]  = (unsigned char)best_k;
    if (out32) out32[o] = best_k;
}

// ---------------------------------------------------------------------------
extern "C" void kernel_launch(void* const* d_in, const int* in_sizes, int n_in,
                              void* d_out, int out_size, void* d_ws, size_t ws_size,
                              hipStream_t stream) {
    const float* grad = (const float*)d_in[0];
    int* out = (int*)d_out;
    char* ws = (char*)d_ws;

    int* cv = (int*)(ws);                               // 25088 B
    int* ch = (int*)(ws + 25088);                       // 25088 B
    unsigned char* laW = (unsigned char*)(ws + 50176);  // ping (ws)
    unsigned char* laD = (unsigned char*)d_out;         // pong (inside d_out)

    dp_kernel<<<56, 64, 0, stream>>>(grad, cv, ch);

    dim3 gridv(WW / 32, HH / 8, BB), blkv(32, 8, 1);
    labvote_kernel<<<gridv, blkv, 0, stream>>>(cv, ch, laD);          // v1 -> laD

    dim3 gridp(WW / 32, HH / 16, BB), blkp(32, 16, 1);
    votepair_kernel<<<gridp, blkp, 0, stream>>>(laD, laW, nullptr);   // v2,v3 -> laW
    votepair_kernel<<<gridp, blkp, 0, stream>>>(laW, nullptr, out);   // v4,v5 -> int out
}

// Round 10
// 119.299 us; speedup vs baseline: 1.1039x; 1.1039x over previous
//
#include <hip/hip_runtime.h>
#include <stdint.h>

#define HH 224
#define WW 224
#define BB 4
#define PP 7          // seams per direction
#define SEG 28
#define BW 5
#define MM 11         // 2*BW+1

#define POS_INF_I 0x7F800000

typedef const __attribute__((address_space(1))) unsigned int* gas_ptr;
typedef __attribute__((address_space(3))) unsigned int* las_ptr;
typedef unsigned long long ull;

// map-compose for 11-entry 4-bit-nibble maps packed in u64:  H[i] = F[G[i]]
__device__ inline ull mcompose(ull F, ull G) {
    ull H = 0ull;
#pragma unroll
    for (int i = 0; i < 11; ++i) {
        unsigned g = (unsigned)(G >> (4 * i)) & 15u;
        H |= ((F >> (4 * g)) & 15ull) << (4 * i);
    }
    return H;
}

// ---------------------------------------------------------------------------
// DP kernel (unchanged from R4 — verified absmax 0)
// ---------------------------------------------------------------------------
__global__ __launch_bounds__(64) void dp_kernel(const float* __restrict__ grad,
                                                int* __restrict__ coords_v,
                                                int* __restrict__ coords_h) {
    __shared__ __align__(16) float gseg[225 * 16];

    const int tid = threadIdx.x;
    const int l   = tid & 15;
    const int sid = blockIdx.x;
    const int p   = sid % PP;
    const int dir = (sid / PP) & 1;
    const int b   = sid / (2 * PP);
    const int base = SEG * (p + 1);
    const float* gb = grad + b * (HH * WW);

    {
        const int r  = tid >> 4;
        const int m  = tid & 15;
        const int sS = (dir == 0) ? WW : 1;
        const int sM = (dir == 0) ? 1  : WW;
        const float* src = gb + r * sS + (base - BW + m) * sM;
        const long stepBytes = (long)(4 * sS) * 4;
#pragma unroll 8
        for (int c = 0; c < 56; ++c) {
            __builtin_amdgcn_global_load_lds((gas_ptr)(const void*)src,
                                             (las_ptr)(void*)(&gseg[c * 64]), 4, 0, 0);
            src = (const float*)((const char*)src + stepBytes);
        }
    }
    __syncthreads();

    const float lane_add = (l < MM) ? 0.0f : __int_as_float(POS_INF_I);
    const float* gp = &gseg[l];

    unsigned wreg[16] = {};

#define DP_STEP(gval, ownb, jj_c)                                                       \
    {                                                                                   \
        float v1 = cost;                                                                \
        float v0 = __int_as_float(__builtin_amdgcn_update_dpp(                          \
            POS_INF_I, __float_as_int(cost), 0x111, 0xf, 0xf, false));                  \
        float v2 = __int_as_float(__builtin_amdgcn_update_dpp(                          \
            POS_INF_I, __float_as_int(cost), 0x101, 0xf, 0xf, false));                  \
        bool a01 = (v0 <= v1), a02 = (v0 <= v2), a12 = (v1 <= v2);                      \
        bool aa  = a01 && a02;                                                          \
        unsigned long long A   = __ballot(aa);                                          \
        unsigned long long C12 = __ballot(a12);                                         \
        unsigned long long B0 = ~A & C12;                                               \
        unsigned long long B1 = ~A & ~C12;                                              \
        float mv = aa ? v0 : (a12 ? v1 : v2);                                           \
        cost = mv - (gval) + lane_add;                                                  \
        unsigned wv = (unsigned)(B0 & 0x7FFull) | ((unsigned)(B1 & 0x7FFull) << 11);    \
        wreg[(jj_c)] = (ownb) ? wv : wreg[(jj_c)];                                      \
    }

    float cost = -gp[0] + lane_add;
    float buf[16], c0[16];
#pragma unroll
    for (int k = 0; k < 16; ++k) buf[k] = gp[(1 + k) * 16];
    for (int t = 0; t < 13; ++t) {
        const bool own = (tid == t);
#pragma unroll
        for (int k = 0; k < 16; ++k) c0[k] = buf[k];
#pragma unroll
        for (int k = 0; k < 16; ++k) buf[k] = gp[(16 * (t + 1) + 1 + k) * 16];
#pragma unroll
        for (int k = 0; k < 16; ++k) DP_STEP(c0[k], own, k)
    }
    {
        const bool own = (tid == 13);
#pragma unroll
        for (int k = 0; k < 15; ++k) DP_STEP(buf[k], own, k)
    }
#undef DP_STEP

    float bc = cost;
    int   bi = l;
#pragma unroll
    for (int mask = 1; mask < 16; mask <<= 1) {
        float oc = __shfl_xor(bc, mask, 16);
        int   oi = __shfl_xor(bi, mask, 16);
        if (oc < bc || (oc == bc && oi < bi)) { bc = oc; bi = oi; }
    }
    const int idx_last = bi;

    const int mcnt = (l < 13) ? 16 : ((l == 13) ? 15 : 0);
    const ull IDMAP = 0xA9876543210ull;
    ull L = IDMAP;
#pragma unroll
    for (int jj = 15; jj >= 0; --jj) {
        if (jj < mcnt) {
            unsigned ww = wreg[jj];
            ull M = 0ull;
#pragma unroll
            for (int i = 0; i < MM; ++i) {
                unsigned sel = ((ww >> i) & 1u) + 2u * ((ww >> (11 + i)) & 1u);
                M |= ((ull)(i + (int)sel - 1)) << (4 * i);
            }
            L = mcompose(M, L);
        }
    }
    ull I = L;
#pragma unroll
    for (int d = 1; d < 16; d <<= 1) {
        ull O = __shfl_down(I, d, 16);
        if (l + d < 16) I = mcompose(I, O);
    }
    ull R = __shfl_down(I, 1, 16);
    if (l == 15) R = IDMAP;

    int* cout = (dir == 0) ? coords_v : coords_h;
    if (tid == 15) cout[(b * HH + 223) * PP + p] = base + idx_last - BW;
    if (tid < 16) {
        unsigned v = (unsigned)(R >> (4 * idx_last)) & 15u;
#pragma unroll
        for (int jj = 15; jj >= 0; --jj) {
            if (jj < mcnt) {
                unsigned ww = wreg[jj];
                unsigned sel = ((ww >> v) & 1u) + 2u * ((ww >> (11 + v)) & 1u);
                v = v + sel - 1u;
                cout[(b * HH + (16 * l + jj)) * PP + p] = base + (int)v - BW;
            }
        }
    }
}

// ---------------------------------------------------------------------------
// labvote: initial labels (analytic, 38x14 LDS region) + vote iteration 1.
// Unchanged from R8 (proven). Grid (7,28,4) x (32,8).
// ---------------------------------------------------------------------------
#define RW 38
#define RH 14
#define RSTR 40

__global__ __launch_bounds__(256) void labvote_kernel(const int* __restrict__ cv,
                                                      const int* __restrict__ ch,
                                                      unsigned char* __restrict__ out8) {
    __shared__ unsigned char lab[RH * RSTR];
    __shared__ unsigned bins[16 * 256];
    const int tx = threadIdx.x, ty = threadIdx.y;
    const int t  = ty * 32 + tx;
    const int b  = blockIdx.z;
    const int GX0 = blockIdx.x * 32, GY0 = blockIdx.y * 8;

    for (int idx = t; idx < RW * RH; idx += 256) {
        int j = idx / RW, i = idx - j * RW;
        int gx = GX0 - 3 + i, gy = GY0 - 3 + j;
        if ((unsigned)gx < WW && (unsigned)gy < HH) {
            const int* cvp = cv + (b * HH + gy) * PP;
            const int* chp = ch + (b * WW + gx) * PP;
            int v = 0, h = 0;
#pragma unroll
            for (int q = 0; q < PP; ++q) { v += (cvp[q] <= gx); h += (chp[q] <= gy); }
            lab[j * RSTR + i] = (unsigned char)(v + 8 * h);
        }
    }
    __syncthreads();

    const int gx = GX0 + tx, gy = GY0 + ty;
#pragma unroll
    for (int c = 0; c < 16; ++c) bins[c * 256 + t] = 0u;
#pragma unroll
    for (int dy = -3; dy <= 3; ++dy) {
        if ((unsigned)(gy + dy) >= HH) continue;
#pragma unroll
        for (int dx = -3; dx <= 3; ++dx) {
            if ((unsigned)(gx + dx) >= WW) continue;
            int lb = lab[(ty + 3 + dy) * RSTR + (tx + 3 + dx)];
            int ay = dy < 0 ? -dy : dy, ax = dx < 0 ? -dx : dx;
            int d = ay > ax ? ay : ax;
            unsigned wgt = (d <= 1) ? 3u : (unsigned)(4 - d);
            atomicAdd(&bins[(lb >> 2) * 256 + t], wgt << ((lb & 3) * 8));
        }
    }
    int best_s = 0, best_k = 0;
#pragma unroll
    for (int c = 0; c < 16; ++c) {
        unsigned wd = bins[c * 256 + t];
        if (wd) {
#pragma unroll
            for (int q = 0; q < 4; ++q) {
                int s = (int)((wd >> (q * 8)) & 255u);
                if (s > best_s) { best_s = s; best_k = c * 4 + q; }
            }
        }
    }
    out8[(b * HH + gy) * WW + gx] = (unsigned char)best_k;
}

// ---------------------------------------------------------------------------
// vote v3: packed row gather (21 dword loads interior; per-byte on x-edge
// blocks) + uniform-window fast path; R5/R6-proven skip-OOB slow path.
// Grid (7,28,4) x (32,8).
// ---------------------------------------------------------------------------
__global__ __launch_bounds__(256) void vote_kernel(const unsigned char* __restrict__ in,
                                                   unsigned char* __restrict__ out8,
                                                   int* __restrict__ out32) {
    __shared__ unsigned bins[16 * 256];
    const int tx = threadIdx.x, ty = threadIdx.y;
    const int t  = ty * 32 + tx;
    const int x  = blockIdx.x * 32 + tx;
    const int y  = blockIdx.y * 8 + ty;
    const int b  = blockIdx.z;
    const unsigned char* img = in + b * (HH * WW);

    ull rows[7];
    const bool xedge = (blockIdx.x == 0) || (blockIdx.x == (WW / 32 - 1));
    if (!xedge) {
        // interior-x: bytes x-3..x+3 are in-image; 3 aligned dword loads/row
        const unsigned* img32 = (const unsigned*)img;
        const int o0 = x - 3;
#pragma unroll
        for (int dy = -3; dy <= 3; ++dy) {
            int yc = min(max(y + dy, 0), HH - 1);
            int o  = yc * WW + o0;
            int a  = o >> 2;
            int sh = (o & 3) * 8;
            unsigned d0 = img32[a], d1 = img32[a + 1], d2 = img32[a + 2];
            ull lo = ((ull)d1 << 32) | d0;
            ull row = lo >> sh;
            if (sh) row |= (ull)d2 << (64 - sh);
            rows[dy + 3] = row & 0x00FFFFFFFFFFFFFFull;
        }
    } else {
        // x-edge blocks: per-byte clamped gather (R4-proven addressing)
#pragma unroll
        for (int dy = -3; dy <= 3; ++dy) {
            int yc = min(max(y + dy, 0), HH - 1);
            ull row = 0ull;
#pragma unroll
            for (int dx = -3; dx <= 3; ++dx) {
                int xc = min(max(x + dx, 0), WW - 1);
                row |= (ull)img[yc * WW + xc] << (8 * (dx + 3));
            }
            rows[dy + 3] = row;
        }
    }

    const unsigned labc = (unsigned)((rows[3] >> 24) & 255u);   // dy=0, dx=0
    const ull rep = (ull)labc * 0x0001010101010101ull;          // 7 bytes replicated
    bool uni = true;
#pragma unroll
    for (int k = 0; k < 7; ++k) uni = uni && (rows[k] == rep);

    int best_k;
    if (uni) {
        // all clamped-window bytes == center  =>  every valid neighbor == center
        // => center is the unique positive vote => argmax = center. Exact.
        best_k = (int)labc;
    } else {
#pragma unroll
        for (int c = 0; c < 16; ++c) bins[c * 256 + t] = 0u;
#pragma unroll
        for (int dy = -3; dy <= 3; ++dy) {
            if ((unsigned)(y + dy) >= (unsigned)HH) continue;
            ull row = rows[dy + 3];
            const int ay = dy < 0 ? -dy : dy;
#pragma unroll
            for (int dx = -3; dx <= 3; ++dx) {
                if ((unsigned)(x + dx) >= (unsigned)WW) continue;
                int lb = (int)((row >> (8 * (dx + 3))) & 255u);
                const int ax = dx < 0 ? -dx : dx;
                const int d = ay > ax ? ay : ax;
                const unsigned wgt = (d <= 1) ? 3u : (unsigned)(4 - d);
                atomicAdd(&bins[(lb >> 2) * 256 + t], wgt << ((lb & 3) * 8));
            }
        }
        int best_s = 0; best_k = 0;
#pragma unroll
        for (int c = 0; c < 16; ++c) {
            unsigned wd = bins[c * 256 + t];
            if (wd) {
#pragma unroll
                for (int q = 0; q < 4; ++q) {
                    int s = (int)((wd >> (q * 8)) & 255u);
                    if (s > best_s) { best_s = s; best_k = c * 4 + q; }
                }
            }
        }
    }

    int o = (b * HH + y) * WW + x;
    if (out8)  out8[o]  = (unsigned char)best_k;
    if (out32) out32[o] = best_k;
}

// ---------------------------------------------------------------------------
extern "C" void kernel_launch(void* const* d_in, const int* in_sizes, int n_in,
                              void* d_out, int out_size, void* d_ws, size_t ws_size,
                              hipStream_t stream) {
    const float* grad = (const float*)d_in[0];
    int* out = (int*)d_out;
    char* ws = (char*)d_ws;

    int* cv = (int*)(ws);                               // 25088 B
    int* ch = (int*)(ws + 25088);                       // 25088 B
    unsigned char* laW = (unsigned char*)(ws + 50176);  // ping (ws)
    unsigned char* laD = (unsigned char*)d_out;         // pong (inside d_out)

    dp_kernel<<<56, 64, 0, stream>>>(grad, cv, ch);

    dim3 grid(WW / 32, HH / 8, BB), blk(32, 8, 1);
    labvote_kernel<<<grid, blk, 0, stream>>>(cv, ch, laD);        // v1 -> laD
    vote_kernel<<<grid, blk, 0, stream>>>(laD, laW, nullptr);     // v2 -> laW
    vote_kernel<<<grid, blk, 0, stream>>>(laW, laD, nullptr);     // v3 -> laD
    vote_kernel<<<grid, blk, 0, stream>>>(laD, laW, nullptr);     // v4 -> laW
    vote_kernel<<<grid, blk, 0, stream>>>(laW, nullptr, out);     // v5 -> int out
}